// Round 4
// baseline (117.404 us; speedup 1.0000x reference)
//
#include <hip/hip_runtime.h>
#include <stdint.h>

// Sizes: h (8,1024,512) f32, s (8,128,1024)->(1024,1024) f32,
//        Wh (512,128), Ws (1024,128), b,v (128,), out (8,128,1024) f32.
//
// Identity 1: tanh(ps+ph) = 1 - 2/(Eps*Eph + 1),
//   Eps = exp2(2*log2e*ps), Eph = exp2(2*log2e*ph); Eph exp'd in GEMM
//   epilogue, Eps exp'd in attn staging (combines split-K halves + bias).
// Identity 2: sum_a v_a/w_a merged as a rational tree sharing ONE rcp.
//   R7: 8 terms/rcp (30 pk-VALU + 2 rcp per 8 a-terms x 2 x) vs 4/rcp
//   (28 pk + 4 rcp). rcp is an 8-issue-cyc trans op -> -14% attn issue.
//   Overflow-safe: needs mean(ps+ph)>5.5 across 8 terms (~20 sigma).
// R6 finding: v_pk_fma_f32 is FULL-RATE on gfx950 (x-pair packed).
//
// R7 (this round):
//   - attn: 8-term single-rcp rational merge (above).
//   - gemm: XCD-aligned task decode — writer block index ≡ n (mod 8),
//     matching attn's n = bid&7 map, so Eph[n]/psPart[:, n-cols] are
//     produced and consumed on the SAME XCD's L2 (dirty-line handoff,
//     ~5 MB less HBM fetch + faster attn staging). Balance unchanged:
//     exactly 80 blocks/XCD.
//
// Pipeline:
//   1. transpose_cast : WhT[a][c], WsT[a][d] bf16 (k-contiguous A operands)
//   2. gemm_fused     : barrier-free register MFMA GEMM, 640 uniform blocks,
//                       depth-4 register pipeline, split-K for Eps
//   3. attn_softmax   : fused tanh-dot + softmax, 256 blocks x 512 thr,
//                       n-major XCD map, 4y x 2x per thread (x-pair packed)

typedef float  f32x4  __attribute__((ext_vector_type(4)));
typedef float  f32x2  __attribute__((ext_vector_type(2)));
typedef __bf16 bf16x8 __attribute__((ext_vector_type(8)));

#define LOG2E     1.4426950408889634f
#define TWO_LOG2E 2.8853900817779268f

static __device__ __forceinline__ f32x2 sp2(float s) {
    return (f32x2){s, s};
}

// ------------------------------------------------- weight transpose + cast
__global__ void __launch_bounds__(256) transpose_cast(
    const float* __restrict__ Wh, const float* __restrict__ Ws,
    __bf16* __restrict__ WhT, __bf16* __restrict__ WsT)
{
    int bid = blockIdx.x;  // 0..31 -> Wh tiles (512/16), 32..95 -> Ws (1024/16)
    const float* src; __bf16* dst; int K, c0;
    if (bid < 32) { src = Wh; dst = WhT; K = 512;  c0 = bid * 16; }
    else          { src = Ws; dst = WsT; K = 1024; c0 = (bid - 32) * 16; }
    __shared__ float tile[16][129];
    int t = threadIdx.x;
    #pragma unroll
    for (int i = 0; i < 2048; i += 256) {
        int idx = i + t;
        int r = idx >> 7, col = idx & 127;              // 16 rows(c) x 128 cols(a)
        tile[r][col] = src[(size_t)(c0 + r) * 128 + col];
    }
    __syncthreads();
    #pragma unroll
    for (int i = 0; i < 2048; i += 256) {
        int idx = i + t;
        int a = idx >> 4, cc = idx & 15;                // 128 rows(a) x 16 cols(c)
        dst[(size_t)a * K + c0 + cc] = (__bf16)tile[cc][a];
    }
}

// --------------------------------------- barrier-free register MFMA GEMM
// 640 uniform blocks, 256 thr (4 waves). Wave w owns rows mq=w*32
// (2 m-tiles of 16) x the block's 16 cols. Exactly 16 k-steps of 32.
// XCD-aligned decode: block index ≡ n (mod 8) for both task types, so
// the XCD that writes Eph[n]/psPart n-columns is the XCD whose attn
// blocks (bid&7 == n) read them.
// blocks 0..511  : Eph  (n=bid&7, colg=n*1024+(bid>>3)*16, exp2 epilogue)
// blocks 512..639: Eps  (b2=bid-512: n=b2&7, idx=b2>>3, half=idx&1,
//                        colg=n*128+(idx>>1)*16, RAW store to psPart)
__global__ void __launch_bounds__(256) gemm_fused(
    const __bf16* __restrict__ WhT, const __bf16* __restrict__ WsT,
    const float* __restrict__ h, const float* __restrict__ s,
    float* __restrict__ Eph, float* __restrict__ psPart)
{
    int bid = blockIdx.x;
    int tid = threadIdx.x, lane = tid & 63, w = tid >> 6;
    int mq = w * 32;
    int q = lane >> 4, c = lane & 15;

    const __bf16* A; const float* B; float* Cp; int K, kbase, colg; bool isPs;
    if (bid < 512) {
        isPs = false; A = WhT; B = h; K = 512; kbase = 0;
        int n = bid & 7, xg = bid >> 3;
        colg = n * 1024 + xg * 16;             // n = colg>>10, x = colg&1023
        Cp = Eph + (size_t)n * 131072 + xg * 16;   // + m*1024 + col in epilogue
    } else {
        isPs = true; A = WsT; B = s; K = 1024;
        int b2 = bid - 512;
        int n = b2 & 7, idx = b2 >> 3;
        int half = idx & 1; kbase = half * 512;
        colg = n * 128 + (idx >> 1) * 16;
        Cp = psPart + (size_t)half * 131072 + colg;
    }

    const float*  Bp = B + (size_t)(colg + c) * K + kbase + q * 8;
    const __bf16* Ap = A + (size_t)(mq + c) * K + kbase + q * 8;

    f32x4 acc0 = {}, acc1 = {};
    float4 b0s[4], b1s[4];
    bf16x8 a0s[4], a1s[4];
    #pragma unroll
    for (int p = 0; p < 4; ++p) {              // prologue: 4 stages in flight
        int k = p * 32;
        b0s[p] = *(const float4*)(Bp + k);
        b1s[p] = *(const float4*)(Bp + k + 4);
        a0s[p] = *(const bf16x8*)(Ap + k);
        a1s[p] = *(const bf16x8*)(Ap + (size_t)16 * K + k);
    }
    #pragma unroll
    for (int it = 0; it < 16; ++it) {          // fully unrolled: static %4
        int cur = it & 3;
        float4 b0 = b0s[cur], b1 = b1s[cur];
        bf16x8 bf;
        bf[0] = (__bf16)b0.x; bf[1] = (__bf16)b0.y;
        bf[2] = (__bf16)b0.z; bf[3] = (__bf16)b0.w;
        bf[4] = (__bf16)b1.x; bf[5] = (__bf16)b1.y;
        bf[6] = (__bf16)b1.z; bf[7] = (__bf16)b1.w;
        acc0 = __builtin_amdgcn_mfma_f32_16x16x32_bf16(a0s[cur], bf, acc0, 0, 0, 0);
        acc1 = __builtin_amdgcn_mfma_f32_16x16x32_bf16(a1s[cur], bf, acc1, 0, 0, 0);
        if (it + 4 < 16) {                     // refill freed stage slot
            int k = (it + 4) * 32;
            b0s[cur] = *(const float4*)(Bp + k);
            b1s[cur] = *(const float4*)(Bp + k + 4);
            a0s[cur] = *(const bf16x8*)(Ap + k);
            a1s[cur] = *(const bf16x8*)(Ap + (size_t)16 * K + k);
        }
    }

    // C/D layout: col=lane&15, row(within 16-tile)=q*4+r  (m89-verified)
    #pragma unroll
    for (int i = 0; i < 2; ++i) {
        f32x4 av = i ? acc1 : acc0;
        #pragma unroll
        for (int r = 0; r < 4; ++r) {
            int m = mq + i * 16 + q * 4 + r;
            if (isPs) Cp[(size_t)m * 1024 + c] = av[r];
            else      Cp[(size_t)m * 1024 + c] =
                          __builtin_amdgcn_exp2f(av[r] * TWO_LOG2E);
        }
    }
}

// ------------------------------------------- fused tanh-dot + softmax
// 256 blocks (n = bid&7 -> XCD-major: each XCD touches one 512 KB Eph[n]
// slice only, L2-hot from the aligned gemm writers), 512 threads;
// thread t owns x = {2t, 2t+1} and 4 y-rows.
// acc[y] (f32x2 over the x-pair) = sum_a v_a * rcp(w_a),
//   w_a = fma(Eps_y[a], Eph[a][x], 1), 8 a-terms per rcp via a 3-level
//   rational merge tree, all VALU packed-f32 over the x-pair.
// Staging combines the two split-K Eps halves + bias + exp2 for 4 rows.
__global__ void __launch_bounds__(512) attn_softmax(
    const float* __restrict__ Eph, const float* __restrict__ psPart,
    const float* __restrict__ bias, const float* __restrict__ v,
    float* __restrict__ out)
{
    int bid = blockIdx.x;            // 256 blocks = yg(32) x n(8), n minor
    int n = bid & 7, yg = bid >> 3;
    int ny = n * 128 + yg * 4;       // 4 consecutive global rows
    const f32x2* ph2 = (const f32x2*)(Eph + (size_t)n * 131072);
    int t = threadIdx.x;

    __shared__ f32x4 eps4[128];      // {Eps[y0..y3][a]}
    __shared__ f32x4 vv4[32];        // v[a] as float4
    __shared__ float wred[4][8];
    __shared__ float VsumS;

    if (t < 128) {
        f32x4 pa = *(const f32x4*)(psPart + (size_t)t * 1024 + ny);
        f32x4 pb = *(const f32x4*)(psPart + 131072 + (size_t)t * 1024 + ny);
        float bb = bias[t];
        f32x4 pk;
        #pragma unroll
        for (int j = 0; j < 4; ++j)
            pk[j] = __builtin_amdgcn_exp2f((pa[j] + pb[j] + bb) * TWO_LOG2E);
        eps4[t] = pk;
    } else if (t < 160) {
        vv4[t - 128] = *(const f32x4*)(v + (t - 128) * 4);
    }
    if (t >= 448) {                  // last wave computes Vsum (disjoint)
        int l = t - 448;
        float vv = v[l] + v[l + 64];
        for (int m = 32; m; m >>= 1) vv += __shfl_xor(vv, m);
        if (l == 0) VsumS = vv;
    }
    __syncthreads();
    float Vsum = VsumS;

    f32x2 accv[4] = {};
    f32x2 p[8]; f32x4 q[8]; f32x4 vrA, vrB;
    #pragma unroll
    for (int i = 0; i < 8; ++i) p[i] = ph2[i * 512 + t];
    #pragma unroll
    for (int i = 0; i < 8; ++i) q[i] = eps4[i];
    vrA = vv4[0]; vrB = vv4[1];

    for (int a = 0; a < 128; a += 8) {
        int an = (a + 8 < 128) ? a + 8 : a;          // prefetch next group
        f32x2 np[8]; f32x4 nq[8];
        #pragma unroll
        for (int i = 0; i < 8; ++i) np[i] = ph2[(an + i) * 512 + t];
        #pragma unroll
        for (int i = 0; i < 8; ++i) nq[i] = eps4[an + i];
        f32x4 nvrA = vv4[an >> 2], nvrB = vv4[(an >> 2) + 1];

        f32x2 vvp[8];
        #pragma unroll
        for (int i = 0; i < 4; ++i) { vvp[i] = sp2(vrA[i]); vvp[4 + i] = sp2(vrB[i]); }
        f32x2 one = sp2(1.f);
        // 8-term rational tree per (y=j, x-pair): 30 pk-VALU + 2 rcp
        #pragma unroll
        for (int j = 0; j < 4; ++j) {
            f32x2 w0 = __builtin_elementwise_fma(sp2(q[0][j]), p[0], one);
            f32x2 w1 = __builtin_elementwise_fma(sp2(q[1][j]), p[1], one);
            f32x2 w2 = __builtin_elementwise_fma(sp2(q[2][j]), p[2], one);
            f32x2 w3 = __builtin_elementwise_fma(sp2(q[3][j]), p[3], one);
            f32x2 w4 = __builtin_elementwise_fma(sp2(q[4][j]), p[4], one);
            f32x2 w5 = __builtin_elementwise_fma(sp2(q[5][j]), p[5], one);
            f32x2 w6 = __builtin_elementwise_fma(sp2(q[6][j]), p[6], one);
            f32x2 w7 = __builtin_elementwise_fma(sp2(q[7][j]), p[7], one);
            f32x2 d01 = w0 * w1, d23 = w2 * w3, d45 = w4 * w5, d67 = w6 * w7;
            f32x2 n01 = __builtin_elementwise_fma(vvp[1], w0, vvp[0] * w1);
            f32x2 n23 = __builtin_elementwise_fma(vvp[3], w2, vvp[2] * w3);
            f32x2 n45 = __builtin_elementwise_fma(vvp[5], w4, vvp[4] * w5);
            f32x2 n67 = __builtin_elementwise_fma(vvp[7], w6, vvp[6] * w7);
            f32x2 dA = d01 * d23, dB = d45 * d67;
            f32x2 nA = __builtin_elementwise_fma(n23, d01, n01 * d23);
            f32x2 nB = __builtin_elementwise_fma(n67, d45, n45 * d67);
            f32x2 dd = dA * dB;
            f32x2 nn = __builtin_elementwise_fma(nB, dA, nA * dB);
            f32x2 r;
            r.x = __builtin_amdgcn_rcpf(dd.x);
            r.y = __builtin_amdgcn_rcpf(dd.y);
            accv[j] = __builtin_elementwise_fma(nn, r, accv[j]);
        }
        #pragma unroll
        for (int i = 0; i < 8; ++i) { p[i] = np[i]; q[i] = nq[i]; }
        vrA = nvrA; vrB = nvrB;
    }

    float e[4][2];
    #pragma unroll
    for (int j = 0; j < 4; ++j) {
        e[j][0] = fmaf(-2.f, accv[j].x, Vsum);
        e[j][1] = fmaf(-2.f, accv[j].y, Vsum);
    }

    int lane = t & 63, wv = t >> 6;
    float mx[4];
    #pragma unroll
    for (int j = 0; j < 4; ++j) {
        mx[j] = fmaxf(e[j][0], e[j][1]);
        for (int m = 32; m; m >>= 1) mx[j] = fmaxf(mx[j], __shfl_xor(mx[j], m));
    }
    if (lane == 0) {
        #pragma unroll
        for (int j = 0; j < 4; ++j) wred[j][wv] = mx[j];
    }
    __syncthreads();
    #pragma unroll
    for (int j = 0; j < 4; ++j) {
        mx[j] = wred[j][0];
        #pragma unroll
        for (int i = 1; i < 8; ++i) mx[j] = fmaxf(mx[j], wred[j][i]);
    }
    __syncthreads();
    float sx[4][2], sm[4];
    #pragma unroll
    for (int j = 0; j < 4; ++j) {
        sx[j][0] = __builtin_amdgcn_exp2f((e[j][0] - mx[j]) * LOG2E);
        sx[j][1] = __builtin_amdgcn_exp2f((e[j][1] - mx[j]) * LOG2E);
        sm[j] = sx[j][0] + sx[j][1];
        for (int m = 32; m; m >>= 1) sm[j] += __shfl_xor(sm[j], m);
    }
    if (lane == 0) {
        #pragma unroll
        for (int j = 0; j < 4; ++j) wred[j][wv] = sm[j];
    }
    __syncthreads();
    #pragma unroll
    for (int j = 0; j < 4; ++j) {
        float smj = 0.f;
        #pragma unroll
        for (int i = 0; i < 8; ++i) smj += wred[j][i];
        float r = __builtin_amdgcn_rcpf(smj);
        float2 o; o.x = sx[j][0] * r; o.y = sx[j][1] * r;
        ((float2*)(out + (size_t)(ny + j) * 1024))[t] = o;
    }
}

// ----------------------------------------------------------------- launcher
extern "C" void kernel_launch(void* const* d_in, const int* in_sizes, int n_in,
                              void* d_out, int out_size, void* d_ws, size_t ws_size,
                              hipStream_t stream) {
    const float* h  = (const float*)d_in[0];
    const float* s  = (const float*)d_in[1];
    const float* Wh = (const float*)d_in[2];
    const float* Ws = (const float*)d_in[3];
    const float* b  = (const float*)d_in[4];
    const float* v  = (const float*)d_in[5];
    float* out = (float*)d_out;

    char* ws = (char*)d_ws;
    float*  Eph    = (float*)ws;                               // 4 MB
    float*  psPart = (float*)(ws + (4u << 20));                // 1 MB (2 halves)
    __bf16* WhT    = (__bf16*)(ws + (5u << 20));               // 128 KB
    __bf16* WsT    = WhT + (size_t)128 * 512;                  // 256 KB

    transpose_cast<<<96, 256, 0, stream>>>(Wh, Ws, WhT, WsT);
    gemm_fused<<<640, 256, 0, stream>>>(WhT, WsT, h, s, Eph, psPart);
    attn_softmax<<<256, 512, 0, stream>>>(Eph, psPart, b, v, out);
}

// Round 5
// 113.549 us; speedup vs baseline: 1.0339x; 1.0339x over previous
//
#include <hip/hip_runtime.h>
#include <stdint.h>

// Sizes: h (8,1024,512) f32, s (8,128,1024)->(1024,1024) f32,
//        Wh (512,128), Ws (1024,128), b,v (128,), out (8,128,1024) f32.
//
// Identity 1: tanh(ps+ph) = 1 - 2/(Eps*Eph + 1),
//   Eps = exp2(2*log2e*ps), Eph = exp2(2*log2e*ph); Eph exp'd in GEMM
//   epilogue, Eps exp'd in attn staging (combines split-K halves + bias).
// Identity 2: sum_a v_a/w_a over 4 terms shares ONE rcp (14 pk-VALU + 2
//   rcp per 4 a-terms x 2 x) — algebraic floor for this expression shape.
// R6 finding: v_pk_fma_f32 is FULL-RATE on gfx950 (x-pair packed).
// R7 finding: 8-term/rcp merge REGRESSED (+5.6us): p/q/np/nq[8] live-set
//   crosses the 128-VGPR occupancy cliff (2 blk/CU -> 1) — occupancy loss
//   dominates the 0.65us rcp saving. Do not re-attempt without staying
//   under the cliff.
//
// R8 (this round): controlled un-bundle of R7. attn reverted EXACTLY to
//   the R6 4-term packed version; the only delta vs R6 is the gemm
//   XCD-aligned task decode (writer block ≡ n mod 8, matching attn's
//   n = bid&7 reader map -> same-XCD L2 handoff of Eph/psPart).
//
// Pipeline:
//   1. transpose_cast : WhT[a][c], WsT[a][d] bf16 (k-contiguous A operands)
//   2. gemm_fused     : barrier-free register MFMA GEMM, 640 uniform blocks,
//                       depth-4 register pipeline, split-K for Eps
//   3. attn_softmax   : fused tanh-dot + softmax, 256 blocks x 512 thr,
//                       n-major XCD map, 4y x 2x per thread (x-pair packed)

typedef float  f32x4  __attribute__((ext_vector_type(4)));
typedef float  f32x2  __attribute__((ext_vector_type(2)));
typedef __bf16 bf16x8 __attribute__((ext_vector_type(8)));

#define LOG2E     1.4426950408889634f
#define TWO_LOG2E 2.8853900817779268f

static __device__ __forceinline__ f32x2 sp2(float s) {
    return (f32x2){s, s};
}

// ------------------------------------------------- weight transpose + cast
__global__ void __launch_bounds__(256) transpose_cast(
    const float* __restrict__ Wh, const float* __restrict__ Ws,
    __bf16* __restrict__ WhT, __bf16* __restrict__ WsT)
{
    int bid = blockIdx.x;  // 0..31 -> Wh tiles (512/16), 32..95 -> Ws (1024/16)
    const float* src; __bf16* dst; int K, c0;
    if (bid < 32) { src = Wh; dst = WhT; K = 512;  c0 = bid * 16; }
    else          { src = Ws; dst = WsT; K = 1024; c0 = (bid - 32) * 16; }
    __shared__ float tile[16][129];
    int t = threadIdx.x;
    #pragma unroll
    for (int i = 0; i < 2048; i += 256) {
        int idx = i + t;
        int r = idx >> 7, col = idx & 127;              // 16 rows(c) x 128 cols(a)
        tile[r][col] = src[(size_t)(c0 + r) * 128 + col];
    }
    __syncthreads();
    #pragma unroll
    for (int i = 0; i < 2048; i += 256) {
        int idx = i + t;
        int a = idx >> 4, cc = idx & 15;                // 128 rows(a) x 16 cols(c)
        dst[(size_t)a * K + c0 + cc] = (__bf16)tile[cc][a];
    }
}

// --------------------------------------- barrier-free register MFMA GEMM
// 640 uniform blocks, 256 thr (4 waves). Wave w owns rows mq=w*32
// (2 m-tiles of 16) x the block's 16 cols. Exactly 16 k-steps of 32.
// XCD-aligned decode: block index ≡ n (mod 8) for both task types, so
// the XCD that writes Eph[n]/psPart n-columns is the XCD whose attn
// blocks (bid&7 == n) read them.
// blocks 0..511  : Eph  (n=bid&7, colg=n*1024+(bid>>3)*16, exp2 epilogue)
// blocks 512..639: Eps  (b2=bid-512: n=b2&7, idx=b2>>3, half=idx&1,
//                        colg=n*128+(idx>>1)*16, RAW store to psPart)
__global__ void __launch_bounds__(256) gemm_fused(
    const __bf16* __restrict__ WhT, const __bf16* __restrict__ WsT,
    const float* __restrict__ h, const float* __restrict__ s,
    float* __restrict__ Eph, float* __restrict__ psPart)
{
    int bid = blockIdx.x;
    int tid = threadIdx.x, lane = tid & 63, w = tid >> 6;
    int mq = w * 32;
    int q = lane >> 4, c = lane & 15;

    const __bf16* A; const float* B; float* Cp; int K, kbase, colg; bool isPs;
    if (bid < 512) {
        isPs = false; A = WhT; B = h; K = 512; kbase = 0;
        int n = bid & 7, xg = bid >> 3;
        colg = n * 1024 + xg * 16;             // n = colg>>10, x = colg&1023
        Cp = Eph + (size_t)n * 131072 + xg * 16;   // + m*1024 + col in epilogue
    } else {
        isPs = true; A = WsT; B = s; K = 1024;
        int b2 = bid - 512;
        int n = b2 & 7, idx = b2 >> 3;
        int half = idx & 1; kbase = half * 512;
        colg = n * 128 + (idx >> 1) * 16;
        Cp = psPart + (size_t)half * 131072 + colg;
    }

    const float*  Bp = B + (size_t)(colg + c) * K + kbase + q * 8;
    const __bf16* Ap = A + (size_t)(mq + c) * K + kbase + q * 8;

    f32x4 acc0 = {}, acc1 = {};
    float4 b0s[4], b1s[4];
    bf16x8 a0s[4], a1s[4];
    #pragma unroll
    for (int p = 0; p < 4; ++p) {              // prologue: 4 stages in flight
        int k = p * 32;
        b0s[p] = *(const float4*)(Bp + k);
        b1s[p] = *(const float4*)(Bp + k + 4);
        a0s[p] = *(const bf16x8*)(Ap + k);
        a1s[p] = *(const bf16x8*)(Ap + (size_t)16 * K + k);
    }
    #pragma unroll
    for (int it = 0; it < 16; ++it) {          // fully unrolled: static %4
        int cur = it & 3;
        float4 b0 = b0s[cur], b1 = b1s[cur];
        bf16x8 bf;
        bf[0] = (__bf16)b0.x; bf[1] = (__bf16)b0.y;
        bf[2] = (__bf16)b0.z; bf[3] = (__bf16)b0.w;
        bf[4] = (__bf16)b1.x; bf[5] = (__bf16)b1.y;
        bf[6] = (__bf16)b1.z; bf[7] = (__bf16)b1.w;
        acc0 = __builtin_amdgcn_mfma_f32_16x16x32_bf16(a0s[cur], bf, acc0, 0, 0, 0);
        acc1 = __builtin_amdgcn_mfma_f32_16x16x32_bf16(a1s[cur], bf, acc1, 0, 0, 0);
        if (it + 4 < 16) {                     // refill freed stage slot
            int k = (it + 4) * 32;
            b0s[cur] = *(const float4*)(Bp + k);
            b1s[cur] = *(const float4*)(Bp + k + 4);
            a0s[cur] = *(const bf16x8*)(Ap + k);
            a1s[cur] = *(const bf16x8*)(Ap + (size_t)16 * K + k);
        }
    }

    // C/D layout: col=lane&15, row(within 16-tile)=q*4+r  (m89-verified)
    #pragma unroll
    for (int i = 0; i < 2; ++i) {
        f32x4 av = i ? acc1 : acc0;
        #pragma unroll
        for (int r = 0; r < 4; ++r) {
            int m = mq + i * 16 + q * 4 + r;
            if (isPs) Cp[(size_t)m * 1024 + c] = av[r];
            else      Cp[(size_t)m * 1024 + c] =
                          __builtin_amdgcn_exp2f(av[r] * TWO_LOG2E);
        }
    }
}

// ------------------------------------------- fused tanh-dot + softmax
// 256 blocks (n = bid&7 -> XCD-major: each XCD touches one 512 KB Eph[n]
// slice only), 512 threads; thread t owns x = {2t, 2t+1} and 4 y-rows.
// acc[y] (f32x2 over the x-pair) = sum_a v_a * rcp(w_a),
//   w_a = fma(Eps_y[a], Eph[a][x], 1), 4 a-terms per rcp via
//   rational-sum merging, all VALU as packed-f32 over the x-pair.
// Staging combines the two split-K Eps halves + bias + exp2 for 4 rows.
__global__ void __launch_bounds__(512) attn_softmax(
    const float* __restrict__ Eph, const float* __restrict__ psPart,
    const float* __restrict__ bias, const float* __restrict__ v,
    float* __restrict__ out)
{
    int bid = blockIdx.x;            // 256 blocks = yg(32) x n(8), n minor
    int n = bid & 7, yg = bid >> 3;
    int ny = n * 128 + yg * 4;       // 4 consecutive global rows
    const f32x2* ph2 = (const f32x2*)(Eph + (size_t)n * 131072);
    int t = threadIdx.x;

    __shared__ f32x4 eps4[128];      // {Eps[y0..y3][a]}
    __shared__ f32x4 vv4[32];        // v[a] as float4
    __shared__ float wred[4][8];
    __shared__ float VsumS;

    if (t < 128) {
        f32x4 pa = *(const f32x4*)(psPart + (size_t)t * 1024 + ny);
        f32x4 pb = *(const f32x4*)(psPart + 131072 + (size_t)t * 1024 + ny);
        float bb = bias[t];
        f32x4 pk;
        #pragma unroll
        for (int j = 0; j < 4; ++j)
            pk[j] = __builtin_amdgcn_exp2f((pa[j] + pb[j] + bb) * TWO_LOG2E);
        eps4[t] = pk;
    } else if (t < 160) {
        vv4[t - 128] = *(const f32x4*)(v + (t - 128) * 4);
    }
    if (t >= 448) {                  // last wave computes Vsum (disjoint)
        int l = t - 448;
        float vv = v[l] + v[l + 64];
        for (int m = 32; m; m >>= 1) vv += __shfl_xor(vv, m);
        if (l == 0) VsumS = vv;
    }
    __syncthreads();
    float Vsum = VsumS;

    f32x2 accv[4] = {};
    f32x2 p[4]; f32x4 q[4]; f32x4 vr;
    #pragma unroll
    for (int i = 0; i < 4; ++i) p[i] = ph2[i * 512 + t];
    #pragma unroll
    for (int i = 0; i < 4; ++i) q[i] = eps4[i];
    vr = vv4[0];

    #pragma unroll 2
    for (int a = 0; a < 128; a += 4) {
        int an = (a + 4 < 128) ? a + 4 : a;          // prefetch next iter
        f32x2 np[4]; f32x4 nq[4];
        #pragma unroll
        for (int i = 0; i < 4; ++i) np[i] = ph2[(an + i) * 512 + t];
        #pragma unroll
        for (int i = 0; i < 4; ++i) nq[i] = eps4[an + i];
        f32x4 nvr = vv4[an >> 2];

        f32x2 v0 = sp2(vr[0]), v1 = sp2(vr[1]);
        f32x2 v2 = sp2(vr[2]), v3 = sp2(vr[3]);
        f32x2 one = sp2(1.f);
        // 4-term rational sum over the x-pair, packed f32:
        // 14 pk-VALU + 2 rcp covers 4 a-terms x 2 x-outputs
        #pragma unroll
        for (int j = 0; j < 4; ++j) {
            f32x2 w0 = __builtin_elementwise_fma(sp2(q[0][j]), p[0], one);
            f32x2 w1 = __builtin_elementwise_fma(sp2(q[1][j]), p[1], one);
            f32x2 w2 = __builtin_elementwise_fma(sp2(q[2][j]), p[2], one);
            f32x2 w3 = __builtin_elementwise_fma(sp2(q[3][j]), p[3], one);
            f32x2 d01 = w0 * w1, d23 = w2 * w3;
            f32x2 n01 = __builtin_elementwise_fma(v1, w0, v0 * w1);
            f32x2 n23 = __builtin_elementwise_fma(v3, w2, v2 * w3);
            f32x2 dd = d01 * d23;
            f32x2 nn = __builtin_elementwise_fma(n23, d01, n01 * d23);
            f32x2 r;
            r.x = __builtin_amdgcn_rcpf(dd.x);
            r.y = __builtin_amdgcn_rcpf(dd.y);
            accv[j] = __builtin_elementwise_fma(nn, r, accv[j]);
        }
        #pragma unroll
        for (int i = 0; i < 4; ++i) { p[i] = np[i]; q[i] = nq[i]; }
        vr = nvr;
    }

    float e[4][2];
    #pragma unroll
    for (int j = 0; j < 4; ++j) {
        e[j][0] = fmaf(-2.f, accv[j].x, Vsum);
        e[j][1] = fmaf(-2.f, accv[j].y, Vsum);
    }

    int lane = t & 63, wv = t >> 6;
    float mx[4];
    #pragma unroll
    for (int j = 0; j < 4; ++j) {
        mx[j] = fmaxf(e[j][0], e[j][1]);
        for (int m = 32; m; m >>= 1) mx[j] = fmaxf(mx[j], __shfl_xor(mx[j], m));
    }
    if (lane == 0) {
        #pragma unroll
        for (int j = 0; j < 4; ++j) wred[j][wv] = mx[j];
    }
    __syncthreads();
    #pragma unroll
    for (int j = 0; j < 4; ++j) {
        mx[j] = wred[j][0];
        #pragma unroll
        for (int i = 1; i < 8; ++i) mx[j] = fmaxf(mx[j], wred[j][i]);
    }
    __syncthreads();
    float sx[4][2], sm[4];
    #pragma unroll
    for (int j = 0; j < 4; ++j) {
        sx[j][0] = __builtin_amdgcn_exp2f((e[j][0] - mx[j]) * LOG2E);
        sx[j][1] = __builtin_amdgcn_exp2f((e[j][1] - mx[j]) * LOG2E);
        sm[j] = sx[j][0] + sx[j][1];
        for (int m = 32; m; m >>= 1) sm[j] += __shfl_xor(sm[j], m);
    }
    if (lane == 0) {
        #pragma unroll
        for (int j = 0; j < 4; ++j) wred[j][wv] = sm[j];
    }
    __syncthreads();
    #pragma unroll
    for (int j = 0; j < 4; ++j) {
        float smj = 0.f;
        #pragma unroll
        for (int i = 0; i < 8; ++i) smj += wred[j][i];
        float r = __builtin_amdgcn_rcpf(smj);
        float2 o; o.x = sx[j][0] * r; o.y = sx[j][1] * r;
        ((float2*)(out + (size_t)(ny + j) * 1024))[t] = o;
    }
}

// ----------------------------------------------------------------- launcher
extern "C" void kernel_launch(void* const* d_in, const int* in_sizes, int n_in,
                              void* d_out, int out_size, void* d_ws, size_t ws_size,
                              hipStream_t stream) {
    const float* h  = (const float*)d_in[0];
    const float* s  = (const float*)d_in[1];
    const float* Wh = (const float*)d_in[2];
    const float* Ws = (const float*)d_in[3];
    const float* b  = (const float*)d_in[4];
    const float* v  = (const float*)d_in[5];
    float* out = (float*)d_out;

    char* ws = (char*)d_ws;
    float*  Eph    = (float*)ws;                               // 4 MB
    float*  psPart = (float*)(ws + (4u << 20));                // 1 MB (2 halves)
    __bf16* WhT    = (__bf16*)(ws + (5u << 20));               // 128 KB
    __bf16* WsT    = WhT + (size_t)128 * 512;                  // 256 KB

    transpose_cast<<<96, 256, 0, stream>>>(Wh, Ws, WhT, WsT);
    gemm_fused<<<640, 256, 0, stream>>>(WhT, WsT, h, s, Eph, psPart);
    attn_softmax<<<256, 512, 0, stream>>>(Eph, psPart, b, v, out);
}

// Round 6
// 112.442 us; speedup vs baseline: 1.0441x; 1.0098x over previous
//
#include <hip/hip_runtime.h>
#include <stdint.h>

// Sizes: h (8,1024,512) f32, s (8,128,1024)->(1024,1024) f32,
//        Wh (512,128), Ws (1024,128), b,v (128,), out (8,128,1024) f32.
//
// Identity 1: tanh(ps+ph) = 1 - 2/(Eps*Eph + 1),
//   Eps = exp2(2*log2e*ps), Eph = exp2(2*log2e*ph); Eph exp'd in GEMM
//   epilogue, Eps exp'd in attn staging (combines split-K halves + bias).
// Identity 2: sum_a v_a/w_a over 4 terms shares ONE rcp (14 pk-VALU + 2
//   rcp per 4 a-terms x 2 x) — algebraic floor for this expression shape.
// R6 finding: v_pk_fma_f32 is FULL-RATE on gfx950 (x-pair packed).
// R7 finding: 8-term/rcp merge REGRESSED (+3.9us net): p/q/np/nq[8]
//   live-set crosses the 128-VGPR occupancy cliff (2 blk/CU -> 1).
// R8 finding: gemm XCD-aligned decode REGRESSED (+1.7us): gemm streams
//   ~21MB of B through each L2 after writing Eph, evicting the "handoff"
//   lines before attn launches — remap bought nothing, perturbed channel
//   interleave. Linear decode restored.
//
// R9 (this round): exact R6 configuration (best measured, 111.8us) with
//   one delta: transpose_cast at 192 blocks (8-row tiles) — latency-bound
//   kernel, more blocks = shorter serial chain.
//
// Pipeline:
//   1. transpose_cast : WhT[a][c], WsT[a][d] bf16 (k-contiguous A operands)
//   2. gemm_fused     : barrier-free register MFMA GEMM, 640 uniform blocks,
//                       depth-4 register pipeline, split-K for Eps
//   3. attn_softmax   : fused tanh-dot + softmax, 256 blocks x 512 thr,
//                       n-major XCD map, 4y x 2x per thread (x-pair packed)

typedef float  f32x4  __attribute__((ext_vector_type(4)));
typedef float  f32x2  __attribute__((ext_vector_type(2)));
typedef __bf16 bf16x8 __attribute__((ext_vector_type(8)));

#define LOG2E     1.4426950408889634f
#define TWO_LOG2E 2.8853900817779268f

static __device__ __forceinline__ f32x2 sp2(float s) {
    return (f32x2){s, s};
}

// ------------------------------------------------- weight transpose + cast
__global__ void __launch_bounds__(256) transpose_cast(
    const float* __restrict__ Wh, const float* __restrict__ Ws,
    __bf16* __restrict__ WhT, __bf16* __restrict__ WsT)
{
    int bid = blockIdx.x;  // 0..63 -> Wh tiles (512/8), 64..191 -> Ws (1024/8)
    const float* src; __bf16* dst; int K, c0;
    if (bid < 64) { src = Wh; dst = WhT; K = 512;  c0 = bid * 8; }
    else          { src = Ws; dst = WsT; K = 1024; c0 = (bid - 64) * 8; }
    __shared__ float tile[8][129];
    int t = threadIdx.x;
    #pragma unroll
    for (int i = 0; i < 1024; i += 256) {
        int idx = i + t;
        int r = idx >> 7, col = idx & 127;              // 8 rows(c) x 128 cols(a)
        tile[r][col] = src[(size_t)(c0 + r) * 128 + col];
    }
    __syncthreads();
    #pragma unroll
    for (int i = 0; i < 1024; i += 256) {
        int idx = i + t;
        int a = idx >> 3, cc = idx & 7;                 // 128 rows(a) x 8 cols(c)
        dst[(size_t)a * K + c0 + cc] = (__bf16)tile[cc][a];
    }
}

// --------------------------------------- barrier-free register MFMA GEMM
// 640 uniform blocks, 256 thr (4 waves). Wave w owns rows mq=w*32
// (2 m-tiles of 16) x the block's 16 cols. Exactly 16 k-steps of 32.
// blocks 0..511  : Eph  (A=WhT 128x512,  B=h,  colg=bid*16, exp2 epilogue)
// blocks 512..639: Eps  (A=WsT 128x1024, B=s,  split-K half=bit0,
//                        colg=((bid-512)>>1)*16, RAW store to psPart)
__global__ void __launch_bounds__(256) gemm_fused(
    const __bf16* __restrict__ WhT, const __bf16* __restrict__ WsT,
    const float* __restrict__ h, const float* __restrict__ s,
    float* __restrict__ Eph, float* __restrict__ psPart)
{
    int bid = blockIdx.x;
    int tid = threadIdx.x, lane = tid & 63, w = tid >> 6;
    int mq = w * 32;
    int q = lane >> 4, c = lane & 15;

    const __bf16* A; const float* B; float* Cp; int K, kbase, colg; bool isPs;
    if (bid < 512) {
        isPs = false; A = WhT; B = h; K = 512; kbase = 0;
        colg = bid * 16;
        int n = colg >> 10, x = colg & 1023;
        Cp = Eph + (size_t)n * 131072 + x;     // + m*1024 + col in epilogue
    } else {
        isPs = true; A = WsT; B = s; K = 1024;
        int b2 = bid - 512;
        int half = b2 & 1; kbase = half * 512;
        colg = (b2 >> 1) * 16;
        Cp = psPart + (size_t)half * 131072 + colg;
    }

    const float*  Bp = B + (size_t)(colg + c) * K + kbase + q * 8;
    const __bf16* Ap = A + (size_t)(mq + c) * K + kbase + q * 8;

    f32x4 acc0 = {}, acc1 = {};
    float4 b0s[4], b1s[4];
    bf16x8 a0s[4], a1s[4];
    #pragma unroll
    for (int p = 0; p < 4; ++p) {              // prologue: 4 stages in flight
        int k = p * 32;
        b0s[p] = *(const float4*)(Bp + k);
        b1s[p] = *(const float4*)(Bp + k + 4);
        a0s[p] = *(const bf16x8*)(Ap + k);
        a1s[p] = *(const bf16x8*)(Ap + (size_t)16 * K + k);
    }
    #pragma unroll
    for (int it = 0; it < 16; ++it) {          // fully unrolled: static %4
        int cur = it & 3;
        float4 b0 = b0s[cur], b1 = b1s[cur];
        bf16x8 bf;
        bf[0] = (__bf16)b0.x; bf[1] = (__bf16)b0.y;
        bf[2] = (__bf16)b0.z; bf[3] = (__bf16)b0.w;
        bf[4] = (__bf16)b1.x; bf[5] = (__bf16)b1.y;
        bf[6] = (__bf16)b1.z; bf[7] = (__bf16)b1.w;
        acc0 = __builtin_amdgcn_mfma_f32_16x16x32_bf16(a0s[cur], bf, acc0, 0, 0, 0);
        acc1 = __builtin_amdgcn_mfma_f32_16x16x32_bf16(a1s[cur], bf, acc1, 0, 0, 0);
        if (it + 4 < 16) {                     // refill freed stage slot
            int k = (it + 4) * 32;
            b0s[cur] = *(const float4*)(Bp + k);
            b1s[cur] = *(const float4*)(Bp + k + 4);
            a0s[cur] = *(const bf16x8*)(Ap + k);
            a1s[cur] = *(const bf16x8*)(Ap + (size_t)16 * K + k);
        }
    }

    // C/D layout: col=lane&15, row(within 16-tile)=q*4+r  (m89-verified)
    #pragma unroll
    for (int i = 0; i < 2; ++i) {
        f32x4 av = i ? acc1 : acc0;
        #pragma unroll
        for (int r = 0; r < 4; ++r) {
            int m = mq + i * 16 + q * 4 + r;
            if (isPs) Cp[(size_t)m * 1024 + c] = av[r];
            else      Cp[(size_t)m * 1024 + c] =
                          __builtin_amdgcn_exp2f(av[r] * TWO_LOG2E);
        }
    }
}

// ------------------------------------------- fused tanh-dot + softmax
// 256 blocks (n = bid&7 -> XCD-major: each XCD touches one 512 KB Eph[n]
// slice only), 512 threads; thread t owns x = {2t, 2t+1} and 4 y-rows.
// acc[y] (f32x2 over the x-pair) = sum_a v_a * rcp(w_a),
//   w_a = fma(Eps_y[a], Eph[a][x], 1), 4 a-terms per rcp via
//   rational-sum merging, all VALU as packed-f32 over the x-pair.
// Staging combines the two split-K Eps halves + bias + exp2 for 4 rows.
__global__ void __launch_bounds__(512) attn_softmax(
    const float* __restrict__ Eph, const float* __restrict__ psPart,
    const float* __restrict__ bias, const float* __restrict__ v,
    float* __restrict__ out)
{
    int bid = blockIdx.x;            // 256 blocks = yg(32) x n(8), n minor
    int n = bid & 7, yg = bid >> 3;
    int ny = n * 128 + yg * 4;       // 4 consecutive global rows
    const f32x2* ph2 = (const f32x2*)(Eph + (size_t)n * 131072);
    int t = threadIdx.x;

    __shared__ f32x4 eps4[128];      // {Eps[y0..y3][a]}
    __shared__ f32x4 vv4[32];        // v[a] as float4
    __shared__ float wred[4][8];
    __shared__ float VsumS;

    if (t < 128) {
        f32x4 pa = *(const f32x4*)(psPart + (size_t)t * 1024 + ny);
        f32x4 pb = *(const f32x4*)(psPart + 131072 + (size_t)t * 1024 + ny);
        float bb = bias[t];
        f32x4 pk;
        #pragma unroll
        for (int j = 0; j < 4; ++j)
            pk[j] = __builtin_amdgcn_exp2f((pa[j] + pb[j] + bb) * TWO_LOG2E);
        eps4[t] = pk;
    } else if (t < 160) {
        vv4[t - 128] = *(const f32x4*)(v + (t - 128) * 4);
    }
    if (t >= 448) {                  // last wave computes Vsum (disjoint)
        int l = t - 448;
        float vv = v[l] + v[l + 64];
        for (int m = 32; m; m >>= 1) vv += __shfl_xor(vv, m);
        if (l == 0) VsumS = vv;
    }
    __syncthreads();
    float Vsum = VsumS;

    f32x2 accv[4] = {};
    f32x2 p[4]; f32x4 q[4]; f32x4 vr;
    #pragma unroll
    for (int i = 0; i < 4; ++i) p[i] = ph2[i * 512 + t];
    #pragma unroll
    for (int i = 0; i < 4; ++i) q[i] = eps4[i];
    vr = vv4[0];

    #pragma unroll 2
    for (int a = 0; a < 128; a += 4) {
        int an = (a + 4 < 128) ? a + 4 : a;          // prefetch next iter
        f32x2 np[4]; f32x4 nq[4];
        #pragma unroll
        for (int i = 0; i < 4; ++i) np[i] = ph2[(an + i) * 512 + t];
        #pragma unroll
        for (int i = 0; i < 4; ++i) nq[i] = eps4[an + i];
        f32x4 nvr = vv4[an >> 2];

        f32x2 v0 = sp2(vr[0]), v1 = sp2(vr[1]);
        f32x2 v2 = sp2(vr[2]), v3 = sp2(vr[3]);
        f32x2 one = sp2(1.f);
        // 4-term rational sum over the x-pair, packed f32:
        // 14 pk-VALU + 2 rcp covers 4 a-terms x 2 x-outputs
        #pragma unroll
        for (int j = 0; j < 4; ++j) {
            f32x2 w0 = __builtin_elementwise_fma(sp2(q[0][j]), p[0], one);
            f32x2 w1 = __builtin_elementwise_fma(sp2(q[1][j]), p[1], one);
            f32x2 w2 = __builtin_elementwise_fma(sp2(q[2][j]), p[2], one);
            f32x2 w3 = __builtin_elementwise_fma(sp2(q[3][j]), p[3], one);
            f32x2 d01 = w0 * w1, d23 = w2 * w3;
            f32x2 n01 = __builtin_elementwise_fma(v1, w0, v0 * w1);
            f32x2 n23 = __builtin_elementwise_fma(v3, w2, v2 * w3);
            f32x2 dd = d01 * d23;
            f32x2 nn = __builtin_elementwise_fma(n23, d01, n01 * d23);
            f32x2 r;
            r.x = __builtin_amdgcn_rcpf(dd.x);
            r.y = __builtin_amdgcn_rcpf(dd.y);
            accv[j] = __builtin_elementwise_fma(nn, r, accv[j]);
        }
        #pragma unroll
        for (int i = 0; i < 4; ++i) { p[i] = np[i]; q[i] = nq[i]; }
        vr = nvr;
    }

    float e[4][2];
    #pragma unroll
    for (int j = 0; j < 4; ++j) {
        e[j][0] = fmaf(-2.f, accv[j].x, Vsum);
        e[j][1] = fmaf(-2.f, accv[j].y, Vsum);
    }

    int lane = t & 63, wv = t >> 6;
    float mx[4];
    #pragma unroll
    for (int j = 0; j < 4; ++j) {
        mx[j] = fmaxf(e[j][0], e[j][1]);
        for (int m = 32; m; m >>= 1) mx[j] = fmaxf(mx[j], __shfl_xor(mx[j], m));
    }
    if (lane == 0) {
        #pragma unroll
        for (int j = 0; j < 4; ++j) wred[j][wv] = mx[j];
    }
    __syncthreads();
    #pragma unroll
    for (int j = 0; j < 4; ++j) {
        mx[j] = wred[j][0];
        #pragma unroll
        for (int i = 1; i < 8; ++i) mx[j] = fmaxf(mx[j], wred[j][i]);
    }
    __syncthreads();
    float sx[4][2], sm[4];
    #pragma unroll
    for (int j = 0; j < 4; ++j) {
        sx[j][0] = __builtin_amdgcn_exp2f((e[j][0] - mx[j]) * LOG2E);
        sx[j][1] = __builtin_amdgcn_exp2f((e[j][1] - mx[j]) * LOG2E);
        sm[j] = sx[j][0] + sx[j][1];
        for (int m = 32; m; m >>= 1) sm[j] += __shfl_xor(sm[j], m);
    }
    if (lane == 0) {
        #pragma unroll
        for (int j = 0; j < 4; ++j) wred[j][wv] = sm[j];
    }
    __syncthreads();
    #pragma unroll
    for (int j = 0; j < 4; ++j) {
        float smj = 0.f;
        #pragma unroll
        for (int i = 0; i < 8; ++i) smj += wred[j][i];
        float r = __builtin_amdgcn_rcpf(smj);
        float2 o; o.x = sx[j][0] * r; o.y = sx[j][1] * r;
        ((float2*)(out + (size_t)(ny + j) * 1024))[t] = o;
    }
}

// ----------------------------------------------------------------- launcher
extern "C" void kernel_launch(void* const* d_in, const int* in_sizes, int n_in,
                              void* d_out, int out_size, void* d_ws, size_t ws_size,
                              hipStream_t stream) {
    const float* h  = (const float*)d_in[0];
    const float* s  = (const float*)d_in[1];
    const float* Wh = (const float*)d_in[2];
    const float* Ws = (const float*)d_in[3];
    const float* b  = (const float*)d_in[4];
    const float* v  = (const float*)d_in[5];
    float* out = (float*)d_out;

    char* ws = (char*)d_ws;
    float*  Eph    = (float*)ws;                               // 4 MB
    float*  psPart = (float*)(ws + (4u << 20));                // 1 MB (2 halves)
    __bf16* WhT    = (__bf16*)(ws + (5u << 20));               // 128 KB
    __bf16* WsT    = WhT + (size_t)128 * 512;                  // 256 KB

    transpose_cast<<<192, 256, 0, stream>>>(Wh, Ws, WhT, WsT);
    gemm_fused<<<640, 256, 0, stream>>>(WhT, WsT, h, s, Eph, psPart);
    attn_softmax<<<256, 512, 0, stream>>>(Eph, psPart, b, v, out);
}